// Round 9
// baseline (244.927 us; speedup 1.0000x reference)
//
#include <hip/hip_runtime.h>
#include <hip/hip_bf16.h>

#define NMODELS 64
#define BBATCH  4096
#define IN_DIM  64
#define H_DIM   256

typedef __attribute__((ext_vector_type(8))) short short8;
typedef __attribute__((ext_vector_type(4))) float floatx4;
typedef __attribute__((ext_vector_type(4))) unsigned int uint4v;
typedef __attribute__((ext_vector_type(2))) unsigned int uint2v;

__device__ __forceinline__ unsigned short f2bf(float f) {
    unsigned int u = __builtin_bit_cast(unsigned int, f);
    return (unsigned short)((u + 0x8000u) >> 16);   // round-half-up, 0.5-ulp
}
// packed fp32x2 -> bf16x2 (v_cvt_pk_bf16_f32), RNE
__device__ __forceinline__ unsigned int pkbf(float a, float b) {
    __hip_bfloat162 h = __float22bfloat162_rn(make_float2(a, b));
    unsigned int u;
    __builtin_memcpy(&u, &h, 4);
    return u;
}

// Weights-stationary fused 3-layer MLP. 512 WGs = 2/CU, one generation.
// WG = (model m, 512-row chunk); 8 iterations of a 64-row tile (T=1).
// Each wave owns h-cols {w*64 + c16*4 + nb} and keeps its W2 slice in
// 128 pinned VGPRs (transposed+cvt from fp32 once, ~2 us, amortized 8x):
// phase 2 has ZERO global loads. W1/biases reloaded per tile from hot L2.
// No prep kernel, no workspace. Outer loop pinned rolled (R8 spill lesson).
__global__ __launch_bounds__(256, 2) void mlp_fused(
    const float* __restrict__ xs,
    const float* __restrict__ W1,   // [M][64][256] fp32 (k-major rows)
    const float* __restrict__ b1,
    const float* __restrict__ W2,   // [M][256][256] fp32
    const float* __restrict__ b2,
    const float* __restrict__ W3,   // [M][256]
    const float* __restrict__ b3,   // [M]
    float* __restrict__ out)        // [M][B]
{
    __shared__ unsigned short h1s[64 * 256];   // 32 KB, XOR-swizzled
    __shared__ float red[4][64];               // 1 KB cross-wave reduce

    const int bid   = blockIdx.x;
    const int m     = (bid & 7) * 8 + ((bid >> 3) & 7);  // 8 models pinned per XCD slot
    const int chunk = bid >> 6;                          // 0..7
    const int tid = threadIdx.x;
    const int w = tid >> 6, lane = tid & 63;
    const int q = lane >> 4, c16 = lane & 15;
    const int sw = c16 & 7;
    const int colbase = w * 64 + c16 * 4;                // lane's 4 h-cols (+nb)

    const float* W1m = W1 + (size_t)m * IN_DIM * H_DIM;
    const float* W2m = W2 + (size_t)m * H_DIM * H_DIM;
    const float b3v = b3[m];

    // ---- one-time: W2 slice -> 128 pinned VGPRs (B-frag layout) ----
    // w2r[kb][nb][j] = bf16( W2[m][kb*32 + q*8 + j][colbase + nb] )
    short8 w2r[8][4];
#pragma unroll
    for (int kb = 0; kb < 8; ++kb)
#pragma unroll
        for (int jh = 0; jh < 2; ++jh) {
            float4 f[4];
#pragma unroll
            for (int j2 = 0; j2 < 4; ++j2)
                f[j2] = *(const float4*)(W2m
                        + (size_t)(kb * 32 + q * 8 + jh * 4 + j2) * H_DIM + colbase);
#pragma unroll
            for (int nb = 0; nb < 4; ++nb)
#pragma unroll
                for (int j2 = 0; j2 < 4; ++j2)
                    w2r[kb][nb][jh * 4 + j2] = (short)f2bf(((const float*)&f[j2])[nb]);
        }

#pragma unroll 1
    for (int it = 0; it < 8; ++it) {
        const int tile = chunk * 8 + it;
        const float* xrow = xs + ((size_t)m * BBATCH + (size_t)tile * 64) * IN_DIM;

        // ---------------- Phase 1: h1 = relu(x @ W1 + b1) ----------------
        floatx4 acc[4][4];
#pragma unroll
        for (int rb = 0; rb < 4; ++rb)
#pragma unroll
            for (int nb = 0; nb < 4; ++nb)
                acc[rb][nb] = (floatx4){0.f, 0.f, 0.f, 0.f};

#pragma unroll
        for (int kb = 0; kb < 2; ++kb) {
            // build this kb's W1 B-frags from fp32 (L2-hot after tile 0)
            short8 bw[4];
#pragma unroll
            for (int jh = 0; jh < 2; ++jh) {
                float4 f[4];
#pragma unroll
                for (int j2 = 0; j2 < 4; ++j2)
                    f[j2] = *(const float4*)(W1m
                            + (size_t)(kb * 32 + q * 8 + jh * 4 + j2) * H_DIM + colbase);
#pragma unroll
                for (int nb = 0; nb < 4; ++nb)
#pragma unroll
                    for (int j2 = 0; j2 < 4; ++j2)
                        bw[nb][jh * 4 + j2] = (short)f2bf(((const float*)&f[j2])[nb]);
            }
#pragma unroll
            for (int rb = 0; rb < 4; ++rb) {
                const float* xp = xrow + (rb * 16 + c16) * IN_DIM + kb * 32 + q * 8;
                float4 v0 = *(const float4*)xp;
                float4 v1 = *(const float4*)(xp + 4);
                uint4v u;
                u[0] = pkbf(v0.x, v0.y); u[1] = pkbf(v0.z, v0.w);
                u[2] = pkbf(v1.x, v1.y); u[3] = pkbf(v1.z, v1.w);
                short8 ax = __builtin_bit_cast(short8, u);
#pragma unroll
                for (int nb = 0; nb < 4; ++nb)
                    acc[rb][nb] = __builtin_amdgcn_mfma_f32_16x16x32_bf16(
                        ax, bw[nb], acc[rb][nb], 0, 0, 0);
            }
        }

        {   // epilogue: bias+relu+packed cvt, 8B ds_write, 16B-chunk XOR swizzle
            floatx4 b1v = *(const floatx4*)(b1 + m * H_DIM + colbase);
#pragma unroll
            for (int rb = 0; rb < 4; ++rb)
#pragma unroll
                for (int r = 0; r < 4; ++r) {
                    float v0 = fmaxf(acc[rb][0][r] + b1v[0], 0.f);
                    float v1 = fmaxf(acc[rb][1][r] + b1v[1], 0.f);
                    float v2 = fmaxf(acc[rb][2][r] + b1v[2], 0.f);
                    float v3 = fmaxf(acc[rb][3][r] + b1v[3], 0.f);
                    uint2v u; u[0] = pkbf(v0, v1); u[1] = pkbf(v2, v3);
                    int row = rb * 16 + q * 4 + r;
                    int ch = (w * 8 + (c16 >> 1)) ^ (row & 7);
                    *(uint2v*)((char*)h1s + row * 512 + ch * 16 + (c16 & 1) * 8) = u;
                }
        }
        __syncthreads();                       // barrier A: h1 ready

        // ---------------- Phase 2: h2 = relu(h1 @ W2 + b2), W2 in regs --------
#pragma unroll
        for (int rb = 0; rb < 4; ++rb)
#pragma unroll
            for (int nb = 0; nb < 4; ++nb)
                acc[rb][nb] = (floatx4){0.f, 0.f, 0.f, 0.f};

#pragma unroll
        for (int kb = 0; kb < 8; ++kb) {
            short8 av[4];
#pragma unroll
            for (int rb = 0; rb < 4; ++rb)
                av[rb] = *(const short8*)((char*)h1s + (rb * 16 + c16) * 512
                                          + (((kb * 4 + q) ^ sw) * 16));
#pragma unroll
            for (int nb = 0; nb < 4; ++nb)
#pragma unroll
                for (int rb = 0; rb < 4; ++rb)
                    acc[rb][nb] = __builtin_amdgcn_mfma_f32_16x16x32_bf16(
                        av[rb], w2r[kb][nb], acc[rb][nb], 0, 0, 0);
        }

        // ---------------- Phase 3: out = h2 @ W3 + b3 (OUT=1) ----------------
        floatx4 b2v = *(const floatx4*)(b2 + m * H_DIM + colbase);
        floatx4 w3v = *(const floatx4*)(W3 + m * H_DIM + colbase);
        float p[4][4];
#pragma unroll
        for (int rb = 0; rb < 4; ++rb)
#pragma unroll
            for (int r = 0; r < 4; ++r) p[rb][r] = 0.f;
#pragma unroll
        for (int rb = 0; rb < 4; ++rb)
#pragma unroll
            for (int nb = 0; nb < 4; ++nb)
#pragma unroll
                for (int r = 0; r < 4; ++r) {
                    float v = fmaxf(acc[rb][nb][r] + b2v[nb], 0.f);
                    p[rb][r] += v * w3v[nb];
                }
#pragma unroll
        for (int off = 1; off < 16; off <<= 1)
#pragma unroll
            for (int rb = 0; rb < 4; ++rb)
#pragma unroll
                for (int r = 0; r < 4; ++r)
                    p[rb][r] += __shfl_xor(p[rb][r], off);

        if (c16 == 0) {
#pragma unroll
            for (int rb = 0; rb < 4; ++rb)
#pragma unroll
                for (int r = 0; r < 4; ++r)
                    red[w][rb * 16 + q * 4 + r] = p[rb][r];
        }
        __syncthreads();                       // barrier B: red ready, h1 reads done
        if (tid < 64) {
            float s = red[0][tid] + red[1][tid] + red[2][tid] + red[3][tid] + b3v;
            out[(size_t)m * BBATCH + tile * 64 + tid] = s;
        }
    }
}

extern "C" void kernel_launch(void* const* d_in, const int* in_sizes, int n_in,
                              void* d_out, int out_size, void* d_ws, size_t ws_size,
                              hipStream_t stream) {
    const float* xs = (const float*)d_in[0];
    const float* W1 = (const float*)d_in[1];
    const float* b1 = (const float*)d_in[2];
    const float* W2 = (const float*)d_in[3];
    const float* b2 = (const float*)d_in[4];
    const float* W3 = (const float*)d_in[5];
    const float* b3 = (const float*)d_in[6];
    float* out = (float*)d_out;

    mlp_fused<<<512, 256, 0, stream>>>(xs, W1, b1, W2, b2, W3, b3, out);
}

// Round 10
// 214.759 us; speedup vs baseline: 1.1405x; 1.1405x over previous
//
#include <hip/hip_runtime.h>
#include <hip/hip_bf16.h>

#define NMODELS 64
#define BBATCH  4096
#define IN_DIM  64
#define H_DIM   256

typedef __attribute__((ext_vector_type(8))) short short8;
typedef __attribute__((ext_vector_type(4))) float floatx4;
typedef __attribute__((ext_vector_type(4))) unsigned int uint4v;
typedef __attribute__((ext_vector_type(2))) unsigned int uint2v;

__device__ __forceinline__ unsigned short f2bf(float f) {
    unsigned int u = __builtin_bit_cast(unsigned int, f);
    return (unsigned short)((u + 0x8000u) >> 16);
}
__device__ __forceinline__ unsigned int pkbf(float a, float b) {   // v_cvt_pk_bf16_f32, RNE
    __hip_bfloat162 h = __float22bfloat162_rn(make_float2(a, b));
    unsigned int u;
    __builtin_memcpy(&u, &h, 4);
    return u;
}

// blocks 0..255:   W1 [M][64][256] -> w1t [M][256][64] bf16 (transpose+cvt)
// blocks 256..1279: W2 [M][256][256] -> w2t [M][256][256] bf16 (transpose+cvt)
// blocks 1280+ (if launched): xs fp32 -> xsb bf16, straight copy-cvt
__global__ __launch_bounds__(256) void prep_all(const float* __restrict__ W1,
                                                const float* __restrict__ W2,
                                                const float* __restrict__ xs,
                                                unsigned short* __restrict__ w1t,
                                                unsigned short* __restrict__ w2t,
                                                unsigned short* __restrict__ xsb) {
    __shared__ float lds[64][65];
    const int bid = blockIdx.x;
    const int tid = threadIdx.x;
    if (bid >= 1280) {                             // xs convert: 8 elems/thread
        size_t g = ((size_t)(bid - 1280) * 256 + tid) * 8;
        float4 v0 = *(const float4*)(xs + g);
        float4 v1 = *(const float4*)(xs + g + 4);
        uint4v u;
        u[0] = pkbf(v0.x, v0.y); u[1] = pkbf(v0.z, v0.w);
        u[2] = pkbf(v1.x, v1.y); u[3] = pkbf(v1.z, v1.w);
        *(uint4v*)(xsb + g) = u;
        return;
    }
    const float* src;
    unsigned short* dst;
    int K, N, m, kb, nb;
    if (bid < 256) {
        m = bid >> 2; kb = 0; nb = bid & 3; K = IN_DIM; N = H_DIM;
        src = W1; dst = w1t;
    } else {
        int t = bid - 256;
        m = t >> 4; kb = (t >> 2) & 3; nb = t & 3; K = H_DIM; N = H_DIM;
        src = W2; dst = w2t;
    }
    const float* s = src + ((size_t)m * K + (size_t)kb * 64) * N + nb * 64;
    const int r = tid >> 4, c4 = (tid & 15) * 4;
#pragma unroll
    for (int p = 0; p < 4; ++p) {
        int row = p * 16 + r;                      // k-local 0..63
        float4 v = *(const float4*)(s + (size_t)row * N + c4);
        lds[row][c4] = v.x; lds[row][c4 + 1] = v.y;
        lds[row][c4 + 2] = v.z; lds[row][c4 + 3] = v.w;
    }
    __syncthreads();
    unsigned short* dbase = dst + ((size_t)m * N + (size_t)nb * 64) * K + kb * 64;
    const int j = tid & 7;
#pragma unroll
    for (int it = 0; it < 2; ++it) {
        int n = it * 32 + (tid >> 3);
        unsigned short tmp[8];
#pragma unroll
        for (int e = 0; e < 8; ++e) tmp[e] = f2bf(lds[j * 8 + e][n]);
        *(short8*)(dbase + (size_t)n * K + j * 8) = *(const short8*)tmp;
    }
}

// Fused 3-layer MLP: 512 WGs (2/CU, ONE generation), T=2, 4 iterations.
// m = bid&63 -> a model's 8 WGs share an XCD (weights hot in local L2).
// Register diet (R8/R9 lesson: arch-VGPR budget = 256 - 128 acc AGPRs):
// A-frags transient (8 regs), phase-2 t-sequential (av 32), biases
// reloaded per iter. Peak arch live ~75 -> no spill expected.
template <bool XB>
__global__ __launch_bounds__(256, 2) void mlp_fused(
    const float* __restrict__ xs,             // fp32 path (!XB)
    const unsigned short* __restrict__ xsb,   // bf16 path (XB)
    const unsigned short* __restrict__ w1t,   // [M][H][IN] bf16
    const float* __restrict__ b1,
    const unsigned short* __restrict__ w2t,   // [M][H][H] bf16 (n-major)
    const float* __restrict__ b2,
    const float* __restrict__ w3,             // [M][H]
    const float* __restrict__ b3,             // [M]
    float* __restrict__ out)                  // [M][B]
{
    __shared__ unsigned short h1s[2][64 * 256];   // 64 KB
    __shared__ float red[2][4][64];               // 2 KB dedicated

    const int bid   = blockIdx.x;
    const int m     = bid & 63;                   // 8 chunks of m -> same XCD (bid%8 const)
    const int chunk = bid >> 6;                   // 0..7
    const int tid = threadIdx.x;
    const int w = tid >> 6, lane = tid & 63;
    const int q = lane >> 4, c16 = lane & 15;
    const int sw = c16 & 7;
    const int colbase = w * 64 + c16 * 4;

    const unsigned short* w1p = w1t + (size_t)m * (H_DIM * IN_DIM) + colbase * IN_DIM + q * 8;
    const unsigned short* w2p = w2t + (size_t)m * (H_DIM * H_DIM) + colbase * H_DIM + q * 8;
    const float b3v = b3[m];

#pragma unroll 1
    for (int it = 0; it < 4; ++it) {
        const int tile0 = chunk * 8 + it * 2;

        // ---------------- Phase 1: h1[t] = relu(x[t] @ W1 + b1) ----------------
        floatx4 acc[2][4][4];
#pragma unroll
        for (int t = 0; t < 2; ++t)
#pragma unroll
            for (int rb = 0; rb < 4; ++rb)
#pragma unroll
                for (int nb = 0; nb < 4; ++nb)
                    acc[t][rb][nb] = (floatx4){0.f, 0.f, 0.f, 0.f};

#pragma unroll
        for (int kb = 0; kb < 2; ++kb) {
            short8 bw[4];
#pragma unroll
            for (int nb = 0; nb < 4; ++nb)
                bw[nb] = *(const short8*)(w1p + nb * IN_DIM + kb * 32);
#pragma unroll
            for (int t = 0; t < 2; ++t)
#pragma unroll
                for (int rb = 0; rb < 4; ++rb) {
                    const size_t row = (size_t)m * BBATCH + (size_t)(tile0 + t) * 64
                                       + rb * 16 + c16;
                    short8 ax;
                    if constexpr (XB) {
                        ax = *(const short8*)(xsb + row * IN_DIM + kb * 32 + q * 8);
                    } else {
                        const float* xp = xs + row * IN_DIM + kb * 32 + q * 8;
                        float4 v0 = *(const float4*)xp;
                        float4 v1 = *(const float4*)(xp + 4);
                        uint4v u;
                        u[0] = pkbf(v0.x, v0.y); u[1] = pkbf(v0.z, v0.w);
                        u[2] = pkbf(v1.x, v1.y); u[3] = pkbf(v1.z, v1.w);
                        ax = __builtin_bit_cast(short8, u);
                    }
#pragma unroll
                    for (int nb = 0; nb < 4; ++nb)
                        acc[t][rb][nb] = __builtin_amdgcn_mfma_f32_16x16x32_bf16(
                            ax, bw[nb], acc[t][rb][nb], 0, 0, 0);
                }
        }

        {   // epilogue: bias+relu+packed cvt, 8B ds_write, 16B-chunk XOR swizzle
            floatx4 b1v = *(const floatx4*)(b1 + m * H_DIM + colbase);
#pragma unroll
            for (int t = 0; t < 2; ++t)
#pragma unroll
                for (int rb = 0; rb < 4; ++rb)
#pragma unroll
                    for (int r = 0; r < 4; ++r) {
                        float v0 = fmaxf(acc[t][rb][0][r] + b1v[0], 0.f);
                        float v1 = fmaxf(acc[t][rb][1][r] + b1v[1], 0.f);
                        float v2 = fmaxf(acc[t][rb][2][r] + b1v[2], 0.f);
                        float v3 = fmaxf(acc[t][rb][3][r] + b1v[3], 0.f);
                        uint2v u; u[0] = pkbf(v0, v1); u[1] = pkbf(v2, v3);
                        int row = rb * 16 + q * 4 + r;
                        int ch = (w * 8 + (c16 >> 1)) ^ (row & 7);
                        *(uint2v*)((char*)&h1s[t][0] + row * 512 + ch * 16 + (c16 & 1) * 8) = u;
                    }
        }
        __syncthreads();                          // barrier A: h1 ready

        // ---------------- Phase 2: h2[t] = relu(h1[t] @ W2 + b2) ----------------
#pragma unroll
        for (int t = 0; t < 2; ++t)
#pragma unroll
            for (int rb = 0; rb < 4; ++rb)
#pragma unroll
                for (int nb = 0; nb < 4; ++nb)
                    acc[t][rb][nb] = (floatx4){0.f, 0.f, 0.f, 0.f};

#pragma unroll
        for (int kb = 0; kb < 8; ++kb) {
            short8 bv[4];
#pragma unroll
            for (int nb = 0; nb < 4; ++nb)
                bv[nb] = *(const short8*)(w2p + nb * H_DIM + kb * 32);
#pragma unroll
            for (int t = 0; t < 2; ++t) {         // t-sequential: av 32 regs live
                short8 av[4];
#pragma unroll
                for (int rb = 0; rb < 4; ++rb)
                    av[rb] = *(const short8*)((char*)&h1s[t][0] + (rb * 16 + c16) * 512
                                              + (((kb * 4 + q) ^ sw) * 16));
#pragma unroll
                for (int nb = 0; nb < 4; ++nb)
#pragma unroll
                    for (int rb = 0; rb < 4; ++rb)
                        acc[t][rb][nb] = __builtin_amdgcn_mfma_f32_16x16x32_bf16(
                            av[rb], bv[nb], acc[t][rb][nb], 0, 0, 0);
            }
        }

        // ---------------- Phase 3: out = h2 @ W3 + b3 (OUT=1) ----------------
        floatx4 b2v = *(const floatx4*)(b2 + m * H_DIM + colbase);
        floatx4 w3v = *(const floatx4*)(w3 + m * H_DIM + colbase);
        float p[2][4][4];
#pragma unroll
        for (int t = 0; t < 2; ++t)
#pragma unroll
            for (int rb = 0; rb < 4; ++rb)
#pragma unroll
                for (int r = 0; r < 4; ++r) p[t][rb][r] = 0.f;
#pragma unroll
        for (int t = 0; t < 2; ++t)
#pragma unroll
            for (int rb = 0; rb < 4; ++rb)
#pragma unroll
                for (int nb = 0; nb < 4; ++nb)
#pragma unroll
                    for (int r = 0; r < 4; ++r) {
                        float v = fmaxf(acc[t][rb][nb][r] + b2v[nb], 0.f);
                        p[t][rb][r] += v * w3v[nb];
                    }
#pragma unroll
        for (int off = 1; off < 16; off <<= 1)
#pragma unroll
            for (int t = 0; t < 2; ++t)
#pragma unroll
                for (int rb = 0; rb < 4; ++rb)
#pragma unroll
                    for (int r = 0; r < 4; ++r)
                        p[t][rb][r] += __shfl_xor(p[t][rb][r], off);

        if (c16 == 0) {
#pragma unroll
            for (int t = 0; t < 2; ++t)
#pragma unroll
                for (int rb = 0; rb < 4; ++rb)
#pragma unroll
                    for (int r = 0; r < 4; ++r)
                        red[t][w][rb * 16 + q * 4 + r] = p[t][rb][r];
        }
        __syncthreads();                          // barrier B
        if (tid < 128) {
            int t = tid >> 6, rr = tid & 63;
            float s = red[t][0][rr] + red[t][1][rr] + red[t][2][rr] + red[t][3][rr] + b3v;
            out[(size_t)m * BBATCH + (tile0 + t) * 64 + rr] = s;
        }
    }
}

extern "C" void kernel_launch(void* const* d_in, const int* in_sizes, int n_in,
                              void* d_out, int out_size, void* d_ws, size_t ws_size,
                              hipStream_t stream) {
    const float* xs = (const float*)d_in[0];
    const float* W1 = (const float*)d_in[1];
    const float* b1 = (const float*)d_in[2];
    const float* W2 = (const float*)d_in[3];
    const float* b2 = (const float*)d_in[4];
    const float* W3 = (const float*)d_in[5];
    const float* b3 = (const float*)d_in[6];
    float* out = (float*)d_out;

    const size_t W1T_E = (size_t)NMODELS * H_DIM * IN_DIM;    // 1.05M elems
    const size_t W2T_E = (size_t)NMODELS * H_DIM * H_DIM;     // 4.19M
    const size_t XSB_E = (size_t)NMODELS * BBATCH * IN_DIM;   // 16.8M
    unsigned short* w1t = (unsigned short*)d_ws;
    unsigned short* w2t = w1t + W1T_E;
    unsigned short* xsb = w2t + W2T_E;
    const bool use_xb = ws_size >= (W1T_E + W2T_E + XSB_E) * sizeof(unsigned short);

    if (use_xb) {
        prep_all<<<1280 + (int)(XSB_E / (256 * 8)), 256, 0, stream>>>(W1, W2, xs, w1t, w2t, xsb);
        mlp_fused<true><<<512, 256, 0, stream>>>(xs, xsb, w1t, b1, w2t, b2, W3, b3, out);
    } else {
        prep_all<<<1280, 256, 0, stream>>>(W1, W2, xs, w1t, w2t, xsb);
        mlp_fused<false><<<512, 256, 0, stream>>>(xs, xsb, w1t, b1, w2t, b2, W3, b3, out);
    }
}

// Round 11
// 206.953 us; speedup vs baseline: 1.1835x; 1.0377x over previous
//
#include <hip/hip_runtime.h>
#include <hip/hip_bf16.h>

#define NMODELS 64
#define BBATCH  4096
#define IN_DIM  64
#define H_DIM   256

typedef __attribute__((ext_vector_type(8)))  short short8;
typedef __attribute__((ext_vector_type(4)))  float floatx4;
typedef __attribute__((ext_vector_type(16))) float floatx16;
typedef __attribute__((ext_vector_type(4)))  unsigned int uint4v;
typedef __attribute__((ext_vector_type(2)))  unsigned int uint2v;

__device__ __forceinline__ unsigned short f2bf(float f) {
    unsigned int u = __builtin_bit_cast(unsigned int, f);
    return (unsigned short)((u + 0x8000u) >> 16);
}
__device__ __forceinline__ unsigned int pkbf(float a, float b) {   // v_cvt_pk_bf16_f32, RNE
    __hip_bfloat162 h = __float22bfloat162_rn(make_float2(a, b));
    unsigned int u;
    __builtin_memcpy(&u, &h, 4);
    return u;
}

// blocks 0..255:    W1 [M][64][256] -> w1t [M][256][64] bf16 (transpose+cvt)
// blocks 256..1279: W2 [M][256][256] -> w2t [M][256][256] bf16 (transpose+cvt)
// blocks 1280+:     xs fp32 -> xsb bf16 copy-cvt
__global__ __launch_bounds__(256) void prep_all(const float* __restrict__ W1,
                                                const float* __restrict__ W2,
                                                const float* __restrict__ xs,
                                                unsigned short* __restrict__ w1t,
                                                unsigned short* __restrict__ w2t,
                                                unsigned short* __restrict__ xsb) {
    __shared__ float lds[64][65];
    const int bid = blockIdx.x;
    const int tid = threadIdx.x;
    if (bid >= 1280) {
        size_t g = ((size_t)(bid - 1280) * 256 + tid) * 8;
        float4 v0 = *(const float4*)(xs + g);
        float4 v1 = *(const float4*)(xs + g + 4);
        uint4v u;
        u[0] = pkbf(v0.x, v0.y); u[1] = pkbf(v0.z, v0.w);
        u[2] = pkbf(v1.x, v1.y); u[3] = pkbf(v1.z, v1.w);
        *(uint4v*)(xsb + g) = u;
        return;
    }
    const float* src;
    unsigned short* dst;
    int K, N, m, kb, nb;
    if (bid < 256) {
        m = bid >> 2; kb = 0; nb = bid & 3; K = IN_DIM; N = H_DIM;
        src = W1; dst = w1t;
    } else {
        int t = bid - 256;
        m = t >> 4; kb = (t >> 2) & 3; nb = t & 3; K = H_DIM; N = H_DIM;
        src = W2; dst = w2t;
    }
    const float* s = src + ((size_t)m * K + (size_t)kb * 64) * N + nb * 64;
    const int r = tid >> 4, c4 = (tid & 15) * 4;
#pragma unroll
    for (int p = 0; p < 4; ++p) {
        int row = p * 16 + r;
        float4 v = *(const float4*)(s + (size_t)row * N + c4);
        lds[row][c4] = v.x; lds[row][c4 + 1] = v.y;
        lds[row][c4 + 2] = v.z; lds[row][c4 + 3] = v.w;
    }
    __syncthreads();
    unsigned short* dbase = dst + ((size_t)m * N + (size_t)nb * 64) * K + kb * 64;
    const int j = tid & 7;
#pragma unroll
    for (int it = 0; it < 2; ++it) {
        int n = it * 32 + (tid >> 3);
        unsigned short tmp[8];
#pragma unroll
        for (int e = 0; e < 8; ++e) tmp[e] = f2bf(lds[j * 8 + e][n]);
        *(short8*)(dbase + (size_t)n * K + j * 8) = *(const short8*)tmp;
    }
}

// 32x32x16 transposed-dataflow fused MLP. 2048 WGs, 256 thr, T=2, no loop.
// Wave w owns h-cols [w*64,+64) = 2 blocks of 32 (mb). Lane: ln=lane&31,
// l5=lane>>5. Phase 1: D1 = W1^T x^T = h1^T (A[m=hcol][k=in] from w1t,
// B[n=batchrow][k=in] from xsb). C/D (m74/m101): n=lane&31,
// m=(reg&3)+8*(reg>>2)+4*l5 -> 4 h-col-contiguous values per reg-group ->
// 8B LDS writes, h1s[row][hcol] row-major with 8B-chunk XOR swizzle
// (chunk ^ (row&14), preserves 16B pairs). Phase 2: D2 = W2^T h1^T = h2^T.
// Phase 3: lane holds one batch row -> 1 shfl + LDS, no 16-lane tree.
// acc = 8 x floatx16 = 128 AGPR; transient consts -> ~R6 register shape.
template <bool XB>
__global__ __launch_bounds__(256, 2) void mlp_fused(
    const float* __restrict__ xs,
    const unsigned short* __restrict__ xsb,
    const unsigned short* __restrict__ w1t,   // [M][H][IN] bf16
    const float* __restrict__ b1,
    const unsigned short* __restrict__ w2t,   // [M][H][H] bf16 (n-major)
    const float* __restrict__ b2,
    const float* __restrict__ w3,             // [M][H]
    const float* __restrict__ b3,             // [M]
    float* __restrict__ out)                  // [M][B]
{
    __shared__ unsigned short h1s[2][64 * 256];   // 64 KB
    __shared__ float red[2][4][64];               // 2 KB

    const int bid   = blockIdx.x;
    const int m     = bid >> 5;
    const int tile0 = (bid & 31) * 2;
    const int tid = threadIdx.x;
    const int w = tid >> 6, lane = tid & 63;
    const int ln = lane & 31, l5 = lane >> 5;

    const unsigned short* w1m = w1t + (size_t)m * (H_DIM * IN_DIM);
    const unsigned short* w2m = w2t + (size_t)m * (H_DIM * H_DIM);
    const float b3v = b3[m];

    floatx16 acc[2][2][2];                        // [t][mb][nb]
#pragma unroll
    for (int t = 0; t < 2; ++t)
#pragma unroll
        for (int mb = 0; mb < 2; ++mb)
#pragma unroll
            for (int nb = 0; nb < 2; ++nb)
#pragma unroll
                for (int i = 0; i < 16; ++i) acc[t][mb][nb][i] = 0.f;

    // ---------------- Phase 1: h1^T, K=64 in 4 steps of 16 ----------------
#pragma unroll
    for (int ks = 0; ks < 4; ++ks) {
        short8 a1[2];
#pragma unroll
        for (int mb = 0; mb < 2; ++mb)
            a1[mb] = *(const short8*)(w1m + (size_t)(w * 64 + mb * 32 + ln) * IN_DIM
                                      + ks * 16 + l5 * 8);
        short8 xb[2][2];
#pragma unroll
        for (int t = 0; t < 2; ++t)
#pragma unroll
            for (int nb = 0; nb < 2; ++nb) {
                const size_t row = (size_t)m * BBATCH + (size_t)(tile0 + t) * 64
                                   + nb * 32 + ln;
                if constexpr (XB) {
                    xb[t][nb] = *(const short8*)(xsb + row * IN_DIM + ks * 16 + l5 * 8);
                } else {
                    const float* xp = xs + row * IN_DIM + ks * 16 + l5 * 8;
                    float4 v0 = *(const float4*)xp;
                    float4 v1 = *(const float4*)(xp + 4);
                    uint4v u;
                    u[0] = pkbf(v0.x, v0.y); u[1] = pkbf(v0.z, v0.w);
                    u[2] = pkbf(v1.x, v1.y); u[3] = pkbf(v1.z, v1.w);
                    xb[t][nb] = __builtin_bit_cast(short8, u);
                }
            }
#pragma unroll
        for (int t = 0; t < 2; ++t)
#pragma unroll
            for (int mb = 0; mb < 2; ++mb)
#pragma unroll
                for (int nb = 0; nb < 2; ++nb)
                    acc[t][mb][nb] = __builtin_amdgcn_mfma_f32_32x32x16_bf16(
                        a1[mb], xb[t][nb], acc[t][mb][nb], 0, 0, 0);
    }

    {   // epilogue: bias+relu+cvt; reg-group rg holds hcols base+{0..3} -> 8B writes
        floatx4 b1v[2][4];
#pragma unroll
        for (int mb = 0; mb < 2; ++mb)
#pragma unroll
            for (int rg = 0; rg < 4; ++rg)
                b1v[mb][rg] = *(const floatx4*)(b1 + m * H_DIM + w * 64 + mb * 32
                                                + rg * 8 + l5 * 4);
#pragma unroll
        for (int t = 0; t < 2; ++t)
#pragma unroll
            for (int mb = 0; mb < 2; ++mb)
#pragma unroll
                for (int nb = 0; nb < 2; ++nb) {
                    const int row = nb * 32 + ln;
                    char* base = (char*)&h1s[t][0] + row * 512;
                    const int swz = row & 14;
#pragma unroll
                    for (int rg = 0; rg < 4; ++rg) {
                        float v0 = fmaxf(acc[t][mb][nb][rg * 4 + 0] + b1v[mb][rg][0], 0.f);
                        float v1 = fmaxf(acc[t][mb][nb][rg * 4 + 1] + b1v[mb][rg][1], 0.f);
                        float v2 = fmaxf(acc[t][mb][nb][rg * 4 + 2] + b1v[mb][rg][2], 0.f);
                        float v3 = fmaxf(acc[t][mb][nb][rg * 4 + 3] + b1v[mb][rg][3], 0.f);
                        uint2v u; u[0] = pkbf(v0, v1); u[1] = pkbf(v2, v3);
                        const int chunk = (w * 16 + mb * 8 + rg * 2 + l5) ^ swz;
                        *(uint2v*)(base + chunk * 8) = u;
                    }
                }
    }
    __syncthreads();

    // ---------------- Phase 2: h2^T, K=256 in 16 steps of 16 ----------------
#pragma unroll
    for (int t = 0; t < 2; ++t)
#pragma unroll
        for (int mb = 0; mb < 2; ++mb)
#pragma unroll
            for (int nb = 0; nb < 2; ++nb)
#pragma unroll
                for (int i = 0; i < 16; ++i) acc[t][mb][nb][i] = 0.f;

#pragma unroll
    for (int ks = 0; ks < 16; ++ks) {
        short8 a2[2];
#pragma unroll
        for (int mb = 0; mb < 2; ++mb)
            a2[mb] = *(const short8*)(w2m + (size_t)(w * 64 + mb * 32 + ln) * H_DIM
                                      + ks * 16 + l5 * 8);
        short8 hb[2][2];
#pragma unroll
        for (int t = 0; t < 2; ++t)
#pragma unroll
            for (int nb = 0; nb < 2; ++nb) {
                const int row = nb * 32 + ln;
                const int chunk = (ks * 4 + l5 * 2) ^ (row & 14);
                hb[t][nb] = *(const short8*)((char*)&h1s[t][0] + row * 512 + chunk * 8);
            }
#pragma unroll
        for (int t = 0; t < 2; ++t)
#pragma unroll
            for (int mb = 0; mb < 2; ++mb)
#pragma unroll
                for (int nb = 0; nb < 2; ++nb)
                    acc[t][mb][nb] = __builtin_amdgcn_mfma_f32_32x32x16_bf16(
                        a2[mb], hb[t][nb], acc[t][mb][nb], 0, 0, 0);
    }

    // ---------------- Phase 3: out = sum_col relu(h2^T + b2) * w3 + b3 ----------
    {
        floatx4 b2v[2][4], w3v[2][4];
#pragma unroll
        for (int mb = 0; mb < 2; ++mb)
#pragma unroll
            for (int rg = 0; rg < 4; ++rg) {
                b2v[mb][rg] = *(const floatx4*)(b2 + m * H_DIM + w * 64 + mb * 32
                                                + rg * 8 + l5 * 4);
                w3v[mb][rg] = *(const floatx4*)(w3 + m * H_DIM + w * 64 + mb * 32
                                                + rg * 8 + l5 * 4);
            }
        float p[2][2] = {{0.f, 0.f}, {0.f, 0.f}};   // [t][nb], batch row nb*32+ln
#pragma unroll
        for (int t = 0; t < 2; ++t)
#pragma unroll
            for (int mb = 0; mb < 2; ++mb)
#pragma unroll
                for (int nb = 0; nb < 2; ++nb)
#pragma unroll
                    for (int rg = 0; rg < 4; ++rg)
#pragma unroll
                        for (int i = 0; i < 4; ++i) {
                            float v = fmaxf(acc[t][mb][nb][rg * 4 + i] + b2v[mb][rg][i], 0.f);
                            p[t][nb] += v * w3v[mb][rg][i];
                        }
        // combine the two l5 halves (different h-cols, same batch row)
#pragma unroll
        for (int t = 0; t < 2; ++t)
#pragma unroll
            for (int nb = 0; nb < 2; ++nb)
                p[t][nb] += __shfl_xor(p[t][nb], 32);
        if (l5 == 0) {
#pragma unroll
            for (int t = 0; t < 2; ++t)
#pragma unroll
                for (int nb = 0; nb < 2; ++nb)
                    red[t][w][nb * 32 + ln] = p[t][nb];
        }
    }
    __syncthreads();
    if (tid < 128) {
        int t = tid >> 6, rr = tid & 63;
        float s = red[t][0][rr] + red[t][1][rr] + red[t][2][rr] + red[t][3][rr] + b3v;
        out[(size_t)m * BBATCH + (tile0 + t) * 64 + rr] = s;
    }
}

extern "C" void kernel_launch(void* const* d_in, const int* in_sizes, int n_in,
                              void* d_out, int out_size, void* d_ws, size_t ws_size,
                              hipStream_t stream) {
    const float* xs = (const float*)d_in[0];
    const float* W1 = (const float*)d_in[1];
    const float* b1 = (const float*)d_in[2];
    const float* W2 = (const float*)d_in[3];
    const float* b2 = (const float*)d_in[4];
    const float* W3 = (const float*)d_in[5];
    const float* b3 = (const float*)d_in[6];
    float* out = (float*)d_out;

    const size_t W1T_E = (size_t)NMODELS * H_DIM * IN_DIM;
    const size_t W2T_E = (size_t)NMODELS * H_DIM * H_DIM;
    const size_t XSB_E = (size_t)NMODELS * BBATCH * IN_DIM;
    unsigned short* w1t = (unsigned short*)d_ws;
    unsigned short* w2t = w1t + W1T_E;
    unsigned short* xsb = w2t + W2T_E;
    const bool use_xb = ws_size >= (W1T_E + W2T_E + XSB_E) * sizeof(unsigned short);

    if (use_xb) {
        prep_all<<<1280 + (int)(XSB_E / (256 * 8)), 256, 0, stream>>>(W1, W2, xs, w1t, w2t, xsb);
        mlp_fused<true><<<NMODELS * (BBATCH / 128), 256, 0, stream>>>(
            xs, xsb, w1t, b1, w2t, b2, W3, b3, out);
    } else {
        prep_all<<<1280, 256, 0, stream>>>(W1, W2, xs, w1t, w2t, xsb);
        mlp_fused<false><<<NMODELS * (BBATCH / 128), 256, 0, stream>>>(
            xs, xsb, w1t, b1, w2t, b2, W3, b3, out);
    }
}

// Round 12
// 188.282 us; speedup vs baseline: 1.3009x; 1.0992x over previous
//
#include <hip/hip_runtime.h>
#include <hip/hip_bf16.h>

#define NMODELS 64
#define BBATCH  4096
#define IN_DIM  64
#define H_DIM   256

typedef __attribute__((ext_vector_type(8)))  short short8;
typedef __attribute__((ext_vector_type(4)))  float floatx4;
typedef __attribute__((ext_vector_type(16))) float floatx16;
typedef __attribute__((ext_vector_type(4)))  unsigned int uint4v;
typedef __attribute__((ext_vector_type(2)))  unsigned int uint2v;

__device__ __forceinline__ unsigned short f2bf(float f) {
    unsigned int u = __builtin_bit_cast(unsigned int, f);
    return (unsigned short)((u + 0x8000u) >> 16);
}
__device__ __forceinline__ unsigned int pkbf(float a, float b) {   // v_cvt_pk_bf16_f32, RNE
    __hip_bfloat162 h = __float22bfloat162_rn(make_float2(a, b));
    unsigned int u;
    __builtin_memcpy(&u, &h, 4);
    return u;
}

// blocks 0..255:    W1 [M][64][256] -> w1t [M][256][64] bf16 (transpose+cvt)
// blocks 256..1279: W2 [M][256][256] -> w2t [M][256][256] bf16 (transpose+cvt)
// blocks 1280+:     xs fp32 -> xsb bf16 copy-cvt
__global__ __launch_bounds__(256) void prep_all(const float* __restrict__ W1,
                                                const float* __restrict__ W2,
                                                const float* __restrict__ xs,
                                                unsigned short* __restrict__ w1t,
                                                unsigned short* __restrict__ w2t,
                                                unsigned short* __restrict__ xsb) {
    __shared__ float lds[64][65];
    const int bid = blockIdx.x;
    const int tid = threadIdx.x;
    if (bid >= 1280) {
        size_t g = ((size_t)(bid - 1280) * 256 + tid) * 8;
        float4 v0 = *(const float4*)(xs + g);
        float4 v1 = *(const float4*)(xs + g + 4);
        uint4v u;
        u[0] = pkbf(v0.x, v0.y); u[1] = pkbf(v0.z, v0.w);
        u[2] = pkbf(v1.x, v1.y); u[3] = pkbf(v1.z, v1.w);
        *(uint4v*)(xsb + g) = u;
        return;
    }
    const float* src;
    unsigned short* dst;
    int K, N, m, kb, nb;
    if (bid < 256) {
        m = bid >> 2; kb = 0; nb = bid & 3; K = IN_DIM; N = H_DIM;
        src = W1; dst = w1t;
    } else {
        int t = bid - 256;
        m = t >> 4; kb = (t >> 2) & 3; nb = t & 3; K = H_DIM; N = H_DIM;
        src = W2; dst = w2t;
    }
    const float* s = src + ((size_t)m * K + (size_t)kb * 64) * N + nb * 64;
    const int r = tid >> 4, c4 = (tid & 15) * 4;
#pragma unroll
    for (int p = 0; p < 4; ++p) {
        int row = p * 16 + r;
        float4 v = *(const float4*)(s + (size_t)row * N + c4);
        lds[row][c4] = v.x; lds[row][c4 + 1] = v.y;
        lds[row][c4 + 2] = v.z; lds[row][c4 + 3] = v.w;
    }
    __syncthreads();
    unsigned short* dbase = dst + ((size_t)m * N + (size_t)nb * 64) * K + kb * 64;
    const int j = tid & 7;
#pragma unroll
    for (int it = 0; it < 2; ++it) {
        int n = it * 32 + (tid >> 3);
        unsigned short tmp[8];
#pragma unroll
        for (int e = 0; e < 8; ++e) tmp[e] = f2bf(lds[j * 8 + e][n]);
        *(short8*)(dbase + (size_t)n * K + j * 8) = *(const short8*)tmp;
    }
}

// 32x32x16 transposed-dataflow fused MLP (R11 engine, verified) with the
// spill fixed: b1/b2/w3 staged in LDS (broadcast ds_reads, scoped per-mb)
// instead of 96 arch registers of constants. Register law (R8-R11): at
// 2 waves/SIMD unified budget = 256/wave; acc 128 AGPR leaves 128 arch.
// Peak arch live now ~80.
template <bool XB>
__global__ __launch_bounds__(256, 2) void mlp_fused(
    const float* __restrict__ xs,
    const unsigned short* __restrict__ xsb,
    const unsigned short* __restrict__ w1t,   // [M][H][IN] bf16
    const float* __restrict__ b1,
    const unsigned short* __restrict__ w2t,   // [M][H][H] bf16 (n-major)
    const float* __restrict__ b2,
    const float* __restrict__ w3,             // [M][H]
    const float* __restrict__ b3,             // [M]
    float* __restrict__ out)                  // [M][B]
{
    __shared__ unsigned short h1s[2][64 * 256];   // 64 KB
    __shared__ float red[2][4][64];               // 2 KB
    __shared__ float cb1[H_DIM], cb2[H_DIM], cw3[H_DIM];  // 3 KB consts

    const int bid   = blockIdx.x;
    const int m     = bid >> 5;
    const int tile0 = (bid & 31) * 2;
    const int tid = threadIdx.x;
    const int w = tid >> 6, lane = tid & 63;
    const int ln = lane & 31, l5 = lane >> 5;

    // stage per-model consts to LDS (frees ~96 arch regs vs R11)
    cb1[tid] = b1[m * H_DIM + tid];
    cb2[tid] = b2[m * H_DIM + tid];
    cw3[tid] = w3[m * H_DIM + tid];
    __syncthreads();

    const unsigned short* w1m = w1t + (size_t)m * (H_DIM * IN_DIM);
    const unsigned short* w2m = w2t + (size_t)m * (H_DIM * H_DIM);
    const float b3v = b3[m];

    floatx16 acc[2][2][2];                        // [t][mb][nb] = 128 AGPR
#pragma unroll
    for (int t = 0; t < 2; ++t)
#pragma unroll
        for (int mb = 0; mb < 2; ++mb)
#pragma unroll
            for (int nb = 0; nb < 2; ++nb)
#pragma unroll
                for (int i = 0; i < 16; ++i) acc[t][mb][nb][i] = 0.f;

    // ---------------- Phase 1: h1^T, K=64 in 4 steps of 16 ----------------
#pragma unroll
    for (int ks = 0; ks < 4; ++ks) {
        short8 a1[2];
#pragma unroll
        for (int mb = 0; mb < 2; ++mb)
            a1[mb] = *(const short8*)(w1m + (size_t)(w * 64 + mb * 32 + ln) * IN_DIM
                                      + ks * 16 + l5 * 8);
        short8 xb[2][2];
#pragma unroll
        for (int t = 0; t < 2; ++t)
#pragma unroll
            for (int nb = 0; nb < 2; ++nb) {
                const size_t row = (size_t)m * BBATCH + (size_t)(tile0 + t) * 64
                                   + nb * 32 + ln;
                if constexpr (XB) {
                    xb[t][nb] = *(const short8*)(xsb + row * IN_DIM + ks * 16 + l5 * 8);
                } else {
                    const float* xp = xs + row * IN_DIM + ks * 16 + l5 * 8;
                    float4 v0 = *(const float4*)xp;
                    float4 v1 = *(const float4*)(xp + 4);
                    uint4v u;
                    u[0] = pkbf(v0.x, v0.y); u[1] = pkbf(v0.z, v0.w);
                    u[2] = pkbf(v1.x, v1.y); u[3] = pkbf(v1.z, v1.w);
                    xb[t][nb] = __builtin_bit_cast(short8, u);
                }
            }
#pragma unroll
        for (int t = 0; t < 2; ++t)
#pragma unroll
            for (int mb = 0; mb < 2; ++mb)
#pragma unroll
                for (int nb = 0; nb < 2; ++nb)
                    acc[t][mb][nb] = __builtin_amdgcn_mfma_f32_32x32x16_bf16(
                        a1[mb], xb[t][nb], acc[t][mb][nb], 0, 0, 0);
    }

    // epilogue: bias+relu+cvt; mb-outer so only b1v[4] (16 regs) is live
#pragma unroll
    for (int mb = 0; mb < 2; ++mb) {
        floatx4 b1v[4];
#pragma unroll
        for (int rg = 0; rg < 4; ++rg)
            b1v[rg] = *(const floatx4*)&cb1[w * 64 + mb * 32 + rg * 8 + l5 * 4];
#pragma unroll
        for (int t = 0; t < 2; ++t)
#pragma unroll
            for (int nb = 0; nb < 2; ++nb) {
                const int row = nb * 32 + ln;
                char* base = (char*)&h1s[t][0] + row * 512;
                const int swz = row & 14;
#pragma unroll
                for (int rg = 0; rg < 4; ++rg) {
                    float v0 = fmaxf(acc[t][mb][nb][rg * 4 + 0] + b1v[rg][0], 0.f);
                    float v1 = fmaxf(acc[t][mb][nb][rg * 4 + 1] + b1v[rg][1], 0.f);
                    float v2 = fmaxf(acc[t][mb][nb][rg * 4 + 2] + b1v[rg][2], 0.f);
                    float v3 = fmaxf(acc[t][mb][nb][rg * 4 + 3] + b1v[rg][3], 0.f);
                    uint2v u; u[0] = pkbf(v0, v1); u[1] = pkbf(v2, v3);
                    const int chunk = (w * 16 + mb * 8 + rg * 2 + l5) ^ swz;
                    *(uint2v*)(base + chunk * 8) = u;
                }
            }
    }
    __syncthreads();

    // ---------------- Phase 2: h2^T, K=256 in 16 steps of 16 ----------------
#pragma unroll
    for (int t = 0; t < 2; ++t)
#pragma unroll
        for (int mb = 0; mb < 2; ++mb)
#pragma unroll
            for (int nb = 0; nb < 2; ++nb)
#pragma unroll
                for (int i = 0; i < 16; ++i) acc[t][mb][nb][i] = 0.f;

#pragma unroll
    for (int ks = 0; ks < 16; ++ks) {
        short8 a2[2];
#pragma unroll
        for (int mb = 0; mb < 2; ++mb)
            a2[mb] = *(const short8*)(w2m + (size_t)(w * 64 + mb * 32 + ln) * H_DIM
                                      + ks * 16 + l5 * 8);
        short8 hb[2][2];
#pragma unroll
        for (int t = 0; t < 2; ++t)
#pragma unroll
            for (int nb = 0; nb < 2; ++nb) {
                const int row = nb * 32 + ln;
                const int chunk = (ks * 4 + l5 * 2) ^ (row & 14);
                hb[t][nb] = *(const short8*)((char*)&h1s[t][0] + row * 512 + chunk * 8);
            }
#pragma unroll
        for (int t = 0; t < 2; ++t)
#pragma unroll
            for (int mb = 0; mb < 2; ++mb)
#pragma unroll
                for (int nb = 0; nb < 2; ++nb)
                    acc[t][mb][nb] = __builtin_amdgcn_mfma_f32_32x32x16_bf16(
                        a2[mb], hb[t][nb], acc[t][mb][nb], 0, 0, 0);
    }

    // ---------------- Phase 3: out = sum_col relu(h2^T + b2) * w3 + b3 ----------
    {
        float p[2][2] = {{0.f, 0.f}, {0.f, 0.f}};   // [t][nb], batch row nb*32+ln
#pragma unroll
        for (int mb = 0; mb < 2; ++mb) {
            floatx4 b2v[4], w3v[4];                 // 32 transient regs
#pragma unroll
            for (int rg = 0; rg < 4; ++rg) {
                b2v[rg] = *(const floatx4*)&cb2[w * 64 + mb * 32 + rg * 8 + l5 * 4];
                w3v[rg] = *(const floatx4*)&cw3[w * 64 + mb * 32 + rg * 8 + l5 * 4];
            }
#pragma unroll
            for (int t = 0; t < 2; ++t)
#pragma unroll
                for (int nb = 0; nb < 2; ++nb)
#pragma unroll
                    for (int rg = 0; rg < 4; ++rg)
#pragma unroll
                        for (int i = 0; i < 4; ++i) {
                            float v = fmaxf(acc[t][mb][nb][rg * 4 + i] + b2v[rg][i], 0.f);
                            p[t][nb] += v * w3v[rg][i];
                        }
        }
#pragma unroll
        for (int t = 0; t < 2; ++t)
#pragma unroll
            for (int nb = 0; nb < 2; ++nb)
                p[t][nb] += __shfl_xor(p[t][nb], 32);
        if (l5 == 0) {
#pragma unroll
            for (int t = 0; t < 2; ++t)
#pragma unroll
                for (int nb = 0; nb < 2; ++nb)
                    red[t][w][nb * 32 + ln] = p[t][nb];
        }
    }
    __syncthreads();
    if (tid < 128) {
        int t = tid >> 6, rr = tid & 63;
        float s = red[t][0][rr] + red[t][1][rr] + red[t][2][rr] + red[t][3][rr] + b3v;
        out[(size_t)m * BBATCH + (tile0 + t) * 64 + rr] = s;
    }
}

extern "C" void kernel_launch(void* const* d_in, const int* in_sizes, int n_in,
                              void* d_out, int out_size, void* d_ws, size_t ws_size,
                              hipStream_t stream) {
    const float* xs = (const float*)d_in[0];
    const float* W1 = (const float*)d_in[1];
    const float* b1 = (const float*)d_in[2];
    const float* W2 = (const float*)d_in[3];
    const float* b2 = (const float*)d_in[4];
    const float* W3 = (const float*)d_in[5];
    const float* b3 = (const float*)d_in[6];
    float* out = (float*)d_out;

    const size_t W1T_E = (size_t)NMODELS * H_DIM * IN_DIM;
    const size_t W2T_E = (size_t)NMODELS * H_DIM * H_DIM;
    const size_t XSB_E = (size_t)NMODELS * BBATCH * IN_DIM;
    unsigned short* w1t = (unsigned short*)d_ws;
    unsigned short* w2t = w1t + W1T_E;
    unsigned short* xsb = w2t + W2T_E;
    const bool use_xb = ws_size >= (W1T_E + W2T_E + XSB_E) * sizeof(unsigned short);

    if (use_xb) {
        prep_all<<<1280 + (int)(XSB_E / (256 * 8)), 256, 0, stream>>>(W1, W2, xs, w1t, w2t, xsb);
        mlp_fused<true><<<NMODELS * (BBATCH / 128), 256, 0, stream>>>(
            xs, xsb, w1t, b1, w2t, b2, W3, b3, out);
    } else {
        prep_all<<<1280, 256, 0, stream>>>(W1, W2, xs, w1t, w2t, xsb);
        mlp_fused<false><<<NMODELS * (BBATCH / 128), 256, 0, stream>>>(
            xs, xsb, w1t, b1, w2t, b2, W3, b3, out);
    }
}